// Round 11
// baseline (620.816 us; speedup 1.0000x reference)
//
#include <hip/hip_runtime.h>

#define BATCH 512
#define T 256
#define C 384
#define H 64

typedef __bf16 bf16x8 __attribute__((ext_vector_type(8)));
typedef __bf16 bf16x4 __attribute__((ext_vector_type(4)));
typedef float f32x4 __attribute__((ext_vector_type(4)));

// LDS byte map (144 KB) — same as round 10.
#define WF_OFF 0
#define KS_OFF 0
#define VT_OFF 32768
#define SCR_OFF 65536
#define LDS_BYTES 147456

// ws layout: wT @0 (147456) | chk @4MB (8MB: 4096 blk x 512 thr x 4B) | out-mirror @16MB (33.5MB)
#define CHK_OFF (4u << 20)
#define OUT_OFF (16u << 20)
#define WS_NEED 50331648ull

__global__ void prep_w(const float* __restrict__ Wq, const float* __restrict__ Wk,
                       const float* __restrict__ Wv, __bf16* __restrict__ wT) {
    const int tid = blockIdx.x * 256 + threadIdx.x;   // 9216 threads
    if (tid >= 9216) return;
    const int lane = tid & 63;
    const int f    = tid >> 6;
    const int n    = f & 3;
    const int f2   = f >> 2;
    const int m    = f2 % 3;
    const int kk   = f2 / 3;
    const int l15  = lane & 15;
    const int g    = lane >> 4;
    const int h    = n * 16 + l15;
    const int k0   = kk * 32 + g * 8;
    const float* W = (m == 0) ? Wq : (m == 1) ? Wk : Wv;
    bf16x8 v;
#pragma unroll
    for (int j = 0; j < 8; ++j) v[j] = (__bf16)W[(k0 + j) * H + h];
    reinterpret_cast<bf16x8*>(wT)[tid] = v;
}

// MODE: 0 = real (out -> d_out), 1 = full -> ws mirror, 2 = phase1+epilogue only, 3 = x-stream only
template <bool USE_WT, int MODE>
__global__ __launch_bounds__(512, 2) void head_fused(
    const float* __restrict__ x, const float* __restrict__ Wq,
    const float* __restrict__ Wk, const float* __restrict__ Wv,
    const __bf16* __restrict__ wT, float* __restrict__ outp, float* __restrict__ chk)
{
    __shared__ __align__(16) unsigned char lds[LDS_BYTES];
    const int tid  = threadIdx.x;
    const int w    = tid >> 6;
    const int lane = tid & 63;
    const int l15  = lane & 15;
    const int g    = lane >> 4;
    const int b    = (MODE == 0) ? blockIdx.x : (blockIdx.x & 511);
    const float* xb = x + (size_t)b * T * C;

    const int tile0 = w;        // {w, 15-w}: phase-2 causal chunks per pair == 5 for all w
    const int tile1 = 15 - w;

    // X prefetch: lane(l15,g) reads its own MFMA A-fragment straight from global.
    float4 px[2][2][2];
    auto loadX = [&](int kt) {
#pragma unroll
        for (int j = 0; j < 2; ++j) {
            const int trow = (((j == 0) ? tile0 : tile1) << 4) + l15;
            const float* s_ = xb + trow * C + kt * 64 + (g << 3);
#pragma unroll
            for (int ks = 0; ks < 2; ++ks) {
                px[j][ks][0] = *reinterpret_cast<const float4*>(s_ + (ks << 5));
                px[j][ks][1] = *reinterpret_cast<const float4*>(s_ + (ks << 5) + 4);
            }
        }
    };

    if constexpr (MODE == 3) {
        // ---- ablation: pure x-stream (same access pattern, no LDS/MFMA) ----
        float s = 0.f;
#pragma unroll 1
        for (int kt = 0; kt < 6; ++kt) {
            loadX(kt);
#pragma unroll
            for (int j = 0; j < 2; ++j)
#pragma unroll
                for (int ks = 0; ks < 2; ++ks)
#pragma unroll
                    for (int q = 0; q < 2; ++q)
                        s += px[j][ks][q].x + px[j][ks][q].y + px[j][ks][q].z + px[j][ks][q].w;
        }
        chk[(size_t)blockIdx.x * 512 + tid] = s;
        return;
    }

    f32x4 acc[3][2][4];
#pragma unroll
    for (int m = 0; m < 3; ++m)
#pragma unroll
        for (int j = 0; j < 2; ++j)
#pragma unroll
            for (int n = 0; n < 4; ++n)
                acc[m][j][n] = (f32x4){0.f, 0.f, 0.f, 0.f};

    loadX(0);   // in flight during W staging

    // ---- stage ALL W fragments (144 KB) once ----
    if (USE_WT) {
        const bf16x8* wTv = reinterpret_cast<const bf16x8*>(wT);
#pragma unroll
        for (int ri = 0; ri < 18; ++ri) {
            const int s = (ri << 9) + tid;
            *reinterpret_cast<bf16x8*>(lds + WF_OFF + (s << 4)) = wTv[s];
        }
    } else {
        const float* wm[3] = {Wq, Wk, Wv};
#pragma unroll 1
        for (int ri = 0; ri < 18; ++ri) {
            const int s  = (ri << 9) + tid;
            const int fi = s >> 6, ls = s & 63;
            const int n = fi & 3, q = fi >> 2, m = q % 3, kk = q / 3;
            const int k0 = kk * 32 + ((ls >> 4) << 3);
            const int h  = (n << 4) + (ls & 15);
            bf16x8 v;
#pragma unroll
            for (int j = 0; j < 8; ++j) v[j] = (__bf16)wm[m][(k0 + j) * H + h];
            *reinterpret_cast<bf16x8*>(lds + WF_OFF + (s << 4)) = v;
        }
    }
    __syncthreads();   // barrier 1: WF visible

    // ---------------- Phase 1: barrier-free K-loop ----------------
#pragma unroll 1
    for (int kt = 0; kt < 6; ++kt) {
        bf16x8 af[2][2];
#pragma unroll
        for (int j = 0; j < 2; ++j)
#pragma unroll
            for (int ks = 0; ks < 2; ++ks)
#pragma unroll
                for (int e = 0; e < 4; ++e) {
                    af[j][ks][e]     = (__bf16)px[j][ks][0][e];
                    af[j][ks][e + 4] = (__bf16)px[j][ks][1][e];
                }
        if (kt < 5) loadX(kt + 1);
#pragma unroll
        for (int ks = 0; ks < 2; ++ks)
#pragma unroll
            for (int m = 0; m < 3; ++m)
#pragma unroll
                for (int n = 0; n < 4; ++n) {
                    const int fl = ((kt * 2 + ks) * 3 + m) * 4 + n;
                    const bf16x8 bfr = *reinterpret_cast<const bf16x8*>(
                        lds + WF_OFF + (fl << 10) + (lane << 4));
                    acc[m][0][n] = __builtin_amdgcn_mfma_f32_16x16x32_bf16(af[0][ks], bfr, acc[m][0][n], 0, 0, 0);
                    acc[m][1][n] = __builtin_amdgcn_mfma_f32_16x16x32_bf16(af[1][ks], bfr, acc[m][1][n], 0, 0, 0);
                }
    }
    __syncthreads();   // barrier 2: WF retires to Ks/VT/SCR

    // ---------------- epilogue: K->Ks, V^T->VT, Q->bf16 frags ----------------
    bf16x8 qf[2][2];
    unsigned char* scr = lds + SCR_OFF + (w << 11);
#pragma unroll
    for (int j = 0; j < 2; ++j) {
        const int tb = ((j == 0) ? tile0 : tile1) << 4;
#pragma unroll
        for (int n = 0; n < 4; ++n) {
            const int hcol = (n << 4) + l15;
            bf16x4 pv;
#pragma unroll
            for (int r = 0; r < 4; ++r) pv[r] = (__bf16)acc[2][j][n][r];
            const int trow0 = tb + (g << 2);
            *reinterpret_cast<bf16x4*>(lds + VT_OFF + hcol * 512 + ((2 * trow0) ^ ((hcol & 7) << 4))) = pv;
#pragma unroll
            for (int r = 0; r < 4; ++r) {
                const int trow = trow0 + r;
                *reinterpret_cast<__bf16*>(lds + KS_OFF + trow * 128 + ((2 * hcol) ^ ((trow & 7) << 4))) =
                    (__bf16)acc[1][j][n][r];
            }
        }
#pragma unroll
        for (int n = 0; n < 4; ++n)
#pragma unroll
            for (int r = 0; r < 4; ++r) {
                const int row = (g << 2) + r;
                *reinterpret_cast<__bf16*>(
                    scr + row * 128 + ((2 * ((n << 4) + l15)) ^ ((row & 7) << 4))) = (__bf16)acc[0][j][n][r];
            }
        qf[j][0] = *reinterpret_cast<const bf16x8*>(
            scr + l15 * 128 + (((g << 4) + 0) ^ ((l15 & 7) << 4)));
        qf[j][1] = *reinterpret_cast<const bf16x8*>(
            scr + l15 * 128 + (((g << 4) + 64) ^ ((l15 & 7) << 4)));
    }
    __syncthreads();   // barrier 3: Ks/VT visible

    if constexpr (MODE == 2) {
        // ---- ablation: stop after phase 1 + epilogue; keep everything live ----
        float s = 0.f;
#pragma unroll
        for (int j = 0; j < 2; ++j)
#pragma unroll
            for (int ks = 0; ks < 2; ++ks)
#pragma unroll
                for (int e = 0; e < 8; ++e)
                    s += (float)qf[j][ks][e];
        s += (float)*reinterpret_cast<const __bf16*>(lds + KS_OFF + tid * 64);
        s += (float)*reinterpret_cast<const __bf16*>(lds + VT_OFF + tid * 64);
        chk[(size_t)blockIdx.x * 512 + tid] = s;
        return;
    }

    // ---------------- Phase 2: causal attention (no barriers) ----------------
    const float se = 0.051031036307982884f * 1.4426950408889634f;  // 384^-0.5 * log2(e)

    auto attend = [&](int mt, bf16x8 qfa, bf16x8 qfb) {
        const int mtu = __builtin_amdgcn_readfirstlane(mt);
        const int q0  = mt << 4;
        const int qrow = q0 + (g << 2);

        f32x4 o[4];
#pragma unroll
        for (int nh = 0; nh < 4; ++nh) o[nh] = (f32x4){0.f, 0.f, 0.f, 0.f};
        float ssum[4] = {0.f, 0.f, 0.f, 0.f};

#pragma unroll
        for (int kc = 0; kc < 4; ++kc) {
            if (kc <= (mtu >> 2)) {     // wave-uniform causal skip
                f32x4 sb[4];
#pragma unroll
                for (int n4 = 0; n4 < 4; ++n4) sb[n4] = (f32x4){0.f, 0.f, 0.f, 0.f};
#pragma unroll
                for (int ks4 = 0; ks4 < 2; ++ks4) {
                    const bf16x8 qv = (ks4 == 0) ? qfa : qfb;
#pragma unroll
                    for (int n4 = 0; n4 < 4; ++n4) {
                        const int brow = (kc << 6) + (n4 << 4) + l15;
                        const bf16x8 bfr = *reinterpret_cast<const bf16x8*>(
                            lds + KS_OFF + brow * 128 + (((ks4 << 6) + (g << 4)) ^ ((brow & 7) << 4)));
                        sb[n4] = __builtin_amdgcn_mfma_f32_16x16x32_bf16(qv, bfr, sb[n4], 0, 0, 0);
                    }
                }
#pragma unroll
                for (int n4 = 0; n4 < 4; ++n4) {
                    const int k = (kc << 6) + (n4 << 4) + l15;
#pragma unroll
                    for (int r = 0; r < 4; ++r) {
                        float p = exp2f(sb[n4][r] * se);
                        if (k > qrow + r) p = 0.f;
                        ssum[r] += p;
                        const int prow = (g << 2) + r;
                        *reinterpret_cast<__bf16*>(
                            scr + prow * 128 + ((2 * ((n4 << 4) + l15)) ^ ((prow & 7) << 4))) = (__bf16)p;
                    }
                }
#pragma unroll
                for (int ks4 = 0; ks4 < 2; ++ks4) {
                    const bf16x8 pf = *reinterpret_cast<const bf16x8*>(
                        scr + l15 * 128 + (((ks4 << 6) + (g << 4)) ^ ((l15 & 7) << 4)));
#pragma unroll
                    for (int nh = 0; nh < 4; ++nh) {
                        const int hrow = (nh << 4) + l15;
                        const bf16x8 vb = *reinterpret_cast<const bf16x8*>(
                            lds + VT_OFF + hrow * 512 +
                            (((kc << 7) + (ks4 << 6) + (g << 4)) ^ ((hrow & 7) << 4)));
                        o[nh] = __builtin_amdgcn_mfma_f32_16x16x32_bf16(pf, vb, o[nh], 0, 0, 0);
                    }
                }
            }
        }

#pragma unroll
        for (int d = 1; d < 16; d <<= 1)
#pragma unroll
            for (int r = 0; r < 4; ++r)
                ssum[r] += __shfl_xor(ssum[r], d);

        float inv[4];
#pragma unroll
        for (int r = 0; r < 4; ++r) inv[r] = 1.0f / ssum[r];
        float* ob = outp + ((size_t)b * T + q0) * H;
#pragma unroll
        for (int nh = 0; nh < 4; ++nh)
#pragma unroll
            for (int r = 0; r < 4; ++r)
                ob[((g << 2) + r) * H + (nh << 4) + l15] = o[nh][r] * inv[r];
    };

    attend(tile0, qf[0][0], qf[0][1]);
    attend(tile1, qf[1][0], qf[1][1]);
}

extern "C" void kernel_launch(void* const* d_in, const int* in_sizes, int n_in,
                              void* d_out, int out_size, void* d_ws, size_t ws_size,
                              hipStream_t stream) {
    (void)in_sizes; (void)n_in; (void)out_size;
    const float* x  = (const float*)d_in[0];
    const float* Wk = (const float*)d_in[1];
    const float* Wq = (const float*)d_in[2];
    const float* Wv = (const float*)d_in[3];
    float* out = (float*)d_out;
    const size_t wt_bytes = (size_t)9216 * 8 * sizeof(__bf16);
    if (ws_size >= WS_NEED) {
        char* p = (char*)d_ws;
        __bf16* wT  = (__bf16*)p;
        float* chk  = (float*)(p + CHK_OFF);
        float* outm = (float*)(p + OUT_OFF);
        prep_w<<<dim3(36), dim3(256), 0, stream>>>(Wq, Wk, Wv, wT);
        // real output
        head_fused<true, 0><<<dim3(512), dim3(512), 0, stream>>>(x, Wq, Wk, Wv, wT, out, nullptr);
        // diagnostics (write only to ws; inflated grids so they surface in rocprof top-5)
        head_fused<true, 1><<<dim3(2048), dim3(512), 0, stream>>>(x, Wq, Wk, Wv, wT, outm, nullptr);
        head_fused<true, 2><<<dim3(2048), dim3(512), 0, stream>>>(x, Wq, Wk, Wv, wT, outm, chk);
        head_fused<true, 3><<<dim3(4096), dim3(512), 0, stream>>>(x, Wq, Wk, Wv, wT, outm, chk);
    } else if (ws_size >= wt_bytes) {
        __bf16* wT = (__bf16*)d_ws;
        prep_w<<<dim3(36), dim3(256), 0, stream>>>(Wq, Wk, Wv, wT);
        head_fused<true, 0><<<dim3(512), dim3(512), 0, stream>>>(x, Wq, Wk, Wv, wT, out, nullptr);
    } else {
        head_fused<false, 0><<<dim3(512), dim3(512), 0, stream>>>(x, Wq, Wk, Wv, nullptr, out, nullptr);
    }
}

// Round 12
// 62.117 us; speedup vs baseline: 9.9943x; 9.9943x over previous
//
#include <hip/hip_runtime.h>

#define BATCH 512
#define T 256
#define C 384
#define H 64

typedef __bf16 bf16x8 __attribute__((ext_vector_type(8)));
typedef __bf16 bf16x4 __attribute__((ext_vector_type(4)));
typedef float f32x4 __attribute__((ext_vector_type(4)));

// LDS byte map (80 KB).
// Phase 1: WF @0 (24KB): 24 W B-frags of current kt, frag fl at fl*1024 + lane*16.
// Phase 2 (overwrites WF after barrier):
//   Ks  @0     (32KB): K [256 t][64 pos-c] bf16, row 128B, swz ^((t&7)<<4), c pos-interleaved
//   VT  @32768 (32KB): V^T [64 h][4 c64][64 pos-t] bf16, swz ^((h&7)<<4), t pos-interleaved
//   SCR @65536 (16KB): 8 waves x 2KB [16][64 pos] bf16 swz ^((row&7)<<4) (Q xpose, P stage)
// pos-interleave (within each 64-chunk of the CONTRACTED dim): pos = (idx&15)*4 + idx/16.
// Both QK (over c) and PV (over k) are order-free sums, so A and B sides use the same
// permutation and results are exact. Read expressions are identical to the linear layout.
#define WF_OFF 0
#define KS_OFF 0
#define VT_OFF 32768
#define SCR_OFF 65536
#define LDS_BYTES 81920

// wT: MFMA B-fragments in lane order. frag fi = ((kt*2+ks)*3+m)*4+n,
// 64 lanes x 16B; lane(l15,g) holds W^T[h=n*16+l15][k=kt*64+ks*32+g*8 ..+8].
__global__ void prep_w(const float* __restrict__ Wq, const float* __restrict__ Wk,
                       const float* __restrict__ Wv, __bf16* __restrict__ wT) {
    const int tid = blockIdx.x * 256 + threadIdx.x;   // 9216 threads
    if (tid >= 9216) return;
    const int lane = tid & 63;
    const int f    = tid >> 6;
    const int n    = f & 3;
    const int f2   = f >> 2;
    const int m    = f2 % 3;
    const int kk   = f2 / 3;
    const int l15  = lane & 15;
    const int g    = lane >> 4;
    const int h    = n * 16 + l15;
    const int k0   = kk * 32 + g * 8;
    const float* W = (m == 0) ? Wq : (m == 1) ? Wk : Wv;
    bf16x8 v;
#pragma unroll
    for (int j = 0; j < 8; ++j) v[j] = (__bf16)W[(k0 + j) * H + h];
    reinterpret_cast<bf16x8*>(wT)[tid] = v;
}

template <bool USE_WT>
__global__ __launch_bounds__(512, 2) void head_fused(
    const float* __restrict__ x, const float* __restrict__ Wq,
    const float* __restrict__ Wk, const float* __restrict__ Wv,
    const __bf16* __restrict__ wT, float* __restrict__ out)
{
    __shared__ __align__(16) unsigned char lds[LDS_BYTES];
    const int tid  = threadIdx.x;
    const int w    = tid >> 6;
    const int lane = tid & 63;
    const int l15  = lane & 15;
    const int g    = lane >> 4;
    const int b    = blockIdx.x;
    const float* xb = x + (size_t)b * T * C;
    const float* wm[3] = {Wq, Wk, Wv};
    const bf16x8* wTv = reinterpret_cast<const bf16x8*>(wT);

    const int tile0 = w;        // {w, 15-w}: balanced causal chunks (5 per pair)
    const int tile1 = 15 - w;

    f32x4 acc[3][2][4];
#pragma unroll
    for (int m = 0; m < 3; ++m)
#pragma unroll
        for (int j = 0; j < 2; ++j)
#pragma unroll
            for (int n = 0; n < 4; ++n)
                acc[m][j][n] = (f32x4){0.f, 0.f, 0.f, 0.f};

    // X: direct per-lane A-frag gather (r10-validated): lane(l15,g) reads
    // x[tile*16+l15][kt*64 + ks*32 + g*8 .. +8)
    float4 px[2][2][2];
    auto loadX = [&](int kt) {
#pragma unroll
        for (int j = 0; j < 2; ++j) {
            const int trow = (((j == 0) ? tile0 : tile1) << 4) + l15;
            const float* s_ = xb + trow * C + kt * 64 + (g << 3);
#pragma unroll
            for (int ks = 0; ks < 2; ++ks) {
                px[j][ks][0] = *reinterpret_cast<const float4*>(s_ + (ks << 5));
                px[j][ks][1] = *reinterpret_cast<const float4*>(s_ + (ks << 5) + 4);
            }
        }
    };
    // W: per-kt staging through prefetch regs
    bf16x8 pw[3];
    auto loadW = [&](int kt) {
        if (USE_WT) {
#pragma unroll
            for (int ri = 0; ri < 3; ++ri) pw[ri] = wTv[kt * 1536 + (ri << 9) + tid];
        } else {
#pragma unroll
            for (int ri = 0; ri < 3; ++ri) {
                const int s  = (ri << 9) + tid;
                const int fl = s >> 6, ls = s & 63;
                const int n = fl & 3, q = fl >> 2, m = q % 3, ks = q / 3;
                const int k0 = kt * 64 + ks * 32 + ((ls >> 4) << 3);
                const int h  = (n << 4) + (ls & 15);
                bf16x8 v;
#pragma unroll
                for (int j = 0; j < 8; ++j) v[j] = (__bf16)wm[m][(k0 + j) * H + h];
                pw[ri] = v;
            }
        }
    };

    loadX(0);
    loadW(0);

    // ---------------- Phase 1 ----------------
#pragma unroll 1
    for (int kt = 0; kt < 6; ++kt) {
#pragma unroll
        for (int ri = 0; ri < 3; ++ri)
            *reinterpret_cast<bf16x8*>(lds + WF_OFF + (((ri << 9) + tid) << 4)) = pw[ri];
        if (kt < 5) loadW(kt + 1);
        __syncthreads();

        bf16x8 af[2][2];
#pragma unroll
        for (int j = 0; j < 2; ++j)
#pragma unroll
            for (int ks = 0; ks < 2; ++ks)
#pragma unroll
                for (int e = 0; e < 4; ++e) {
                    af[j][ks][e]     = (__bf16)px[j][ks][0][e];
                    af[j][ks][e + 4] = (__bf16)px[j][ks][1][e];
                }
        if (kt < 5) loadX(kt + 1);

#pragma unroll
        for (int ks = 0; ks < 2; ++ks)
#pragma unroll
            for (int m = 0; m < 3; ++m)
#pragma unroll
                for (int n = 0; n < 4; ++n) {
                    const int fl = ((ks * 3 + m) << 2) + n;
                    const bf16x8 bfr = *reinterpret_cast<const bf16x8*>(
                        lds + WF_OFF + (fl << 10) + (lane << 4));
                    acc[m][0][n] = __builtin_amdgcn_mfma_f32_16x16x32_bf16(af[0][ks], bfr, acc[m][0][n], 0, 0, 0);
                    acc[m][1][n] = __builtin_amdgcn_mfma_f32_16x16x32_bf16(af[1][ks], bfr, acc[m][1][n], 0, 0, 0);
                }
        __syncthreads();   // after last iter: WF retired, safe to overwrite with Ks
    }

    // ---------------- epilogue (pos-interleaved packed writes) ----------------
    // acc D layout: col h = n*16+l15, row t-in-tile = g*4+r.
    bf16x8 qf[2][2];
    unsigned char* scr = lds + SCR_OFF + (w << 11);
#pragma unroll
    for (int j = 0; j < 2; ++j) {
        const int tile = (j == 0) ? tile0 : tile1;
        const int tb   = tile << 4;
        // K: pack 4 n-values (pos = l15*4+n) per r -> b64 writes
#pragma unroll
        for (int r = 0; r < 4; ++r) {
            bf16x4 kv;
#pragma unroll
            for (int n = 0; n < 4; ++n) kv[n] = (__bf16)acc[1][j][n][r];
            const int t = tb + (g << 2) + r;
            *reinterpret_cast<bf16x4*>(lds + KS_OFF + t * 128 + ((l15 << 3) ^ ((t & 7) << 4))) = kv;
        }
        // Q: same packing into wave-local scr, then read frags (pos-consecutive)
#pragma unroll
        for (int r = 0; r < 4; ++r) {
            bf16x4 qv;
#pragma unroll
            for (int n = 0; n < 4; ++n) qv[n] = (__bf16)acc[0][j][n][r];
            const int row = (g << 2) + r;
            *reinterpret_cast<bf16x4*>(scr + row * 128 + ((l15 << 3) ^ ((row & 7) << 4))) = qv;
        }
        qf[j][0] = *reinterpret_cast<const bf16x8*>(
            scr + l15 * 128 + (((g << 4) + 0) ^ ((l15 & 7) << 4)));
        qf[j][1] = *reinterpret_cast<const bf16x8*>(
            scr + l15 * 128 + (((g << 4) + 64) ^ ((l15 & 7) << 4)));
        // V^T: pos-ordered t within each 64-chunk (pos = (t&15)*4 + (t>>4)&3)
        const int tm  = tile & 3;
        const int c64 = tile >> 2;
#pragma unroll
        for (int n = 0; n < 4; ++n) {
            const int h = (n << 4) + l15;
            const int base = VT_OFF + h * 512 + c64 * 128;
#pragma unroll
            for (int r = 0; r < 4; ++r) {
                const int pos = (((g << 2) + r) << 2) + tm;
                *reinterpret_cast<__bf16*>(lds + base + ((pos * 2) ^ ((h & 7) << 4))) =
                    (__bf16)acc[2][j][n][r];
            }
        }
    }
    __syncthreads();   // Ks/VT visible to all waves

    // ---------------- Phase 2: causal attention (no barriers) ----------------
    const float se = 0.051031036307982884f * 1.4426950408889634f;  // 384^-0.5 * log2(e)

    auto attend = [&](int mt, bf16x8 qfa, bf16x8 qfb) {
        const int mtu = __builtin_amdgcn_readfirstlane(mt);
        const int q0  = mt << 4;
        const int qrow = q0 + (g << 2);

        f32x4 o[4];
#pragma unroll
        for (int nh = 0; nh < 4; ++nh) o[nh] = (f32x4){0.f, 0.f, 0.f, 0.f};
        float ssum[4] = {0.f, 0.f, 0.f, 0.f};

#pragma unroll
        for (int kc = 0; kc < 4; ++kc) {
            if (kc <= (mtu >> 2)) {     // wave-uniform causal skip
                f32x4 sb[4];
#pragma unroll
                for (int n4 = 0; n4 < 4; ++n4) sb[n4] = (f32x4){0.f, 0.f, 0.f, 0.f};
                __builtin_amdgcn_s_setprio(1);
#pragma unroll
                for (int ks4 = 0; ks4 < 2; ++ks4) {
                    const bf16x8 qv = (ks4 == 0) ? qfa : qfb;
#pragma unroll
                    for (int n4 = 0; n4 < 4; ++n4) {
                        const int brow = (kc << 6) + (n4 << 4) + l15;
                        const bf16x8 bfr = *reinterpret_cast<const bf16x8*>(
                            lds + KS_OFF + brow * 128 + (((ks4 << 6) + (g << 4)) ^ ((brow & 7) << 4)));
                        sb[n4] = __builtin_amdgcn_mfma_f32_16x16x32_bf16(qv, bfr, sb[n4], 0, 0, 0);
                    }
                }
                __builtin_amdgcn_s_setprio(0);
                // p = exp(s*scale); no max-sub (normalization cancels, |s*scale| small). mask.
                float p[4][4];
#pragma unroll
                for (int n4 = 0; n4 < 4; ++n4) {
                    const int k = (kc << 6) + (n4 << 4) + l15;
#pragma unroll
                    for (int r = 0; r < 4; ++r) {
                        float pv = exp2f(sb[n4][r] * se);
                        if (k > qrow + r) pv = 0.f;
                        ssum[r] += pv;
                        p[n4][r] = pv;
                    }
                }
                // packed P-stage: pos = l15*4 + n4 (matches VT's pos convention)
#pragma unroll
                for (int r = 0; r < 4; ++r) {
                    bf16x4 pk;
#pragma unroll
                    for (int n4 = 0; n4 < 4; ++n4) pk[n4] = (__bf16)p[n4][r];
                    const int row = (g << 2) + r;
                    *reinterpret_cast<bf16x4*>(scr + row * 128 + ((l15 << 3) ^ ((row & 7) << 4))) = pk;
                }
                __builtin_amdgcn_s_setprio(1);
#pragma unroll
                for (int ks4 = 0; ks4 < 2; ++ks4) {
                    const bf16x8 pf = *reinterpret_cast<const bf16x8*>(
                        scr + l15 * 128 + (((ks4 << 6) + (g << 4)) ^ ((l15 & 7) << 4)));
#pragma unroll
                    for (int nh = 0; nh < 4; ++nh) {
                        const int hrow = (nh << 4) + l15;
                        const bf16x8 vb = *reinterpret_cast<const bf16x8*>(
                            lds + VT_OFF + hrow * 512 +
                            (((kc << 7) + (ks4 << 6) + (g << 4)) ^ ((hrow & 7) << 4)));
                        o[nh] = __builtin_amdgcn_mfma_f32_16x16x32_bf16(pf, vb, o[nh], 0, 0, 0);
                    }
                }
                __builtin_amdgcn_s_setprio(0);
            }
        }

#pragma unroll
        for (int d = 1; d < 16; d <<= 1)
#pragma unroll
            for (int r = 0; r < 4; ++r)
                ssum[r] += __shfl_xor(ssum[r], d);

        float inv[4];
#pragma unroll
        for (int r = 0; r < 4; ++r) inv[r] = 1.0f / ssum[r];
        float* ob = out + ((size_t)b * T + q0) * H;
#pragma unroll
        for (int nh = 0; nh < 4; ++nh)
#pragma unroll
            for (int r = 0; r < 4; ++r)
                ob[((g << 2) + r) * H + (nh << 4) + l15] = o[nh][r] * inv[r];
    };

    attend(tile0, qf[0][0], qf[0][1]);
    attend(tile1, qf[1][0], qf[1][1]);
}

extern "C" void kernel_launch(void* const* d_in, const int* in_sizes, int n_in,
                              void* d_out, int out_size, void* d_ws, size_t ws_size,
                              hipStream_t stream) {
    (void)in_sizes; (void)n_in; (void)out_size;
    const float* x  = (const float*)d_in[0];
    const float* Wk = (const float*)d_in[1];
    const float* Wq = (const float*)d_in[2];
    const float* Wv = (const float*)d_in[3];
    float* out = (float*)d_out;
    const size_t wt_bytes = (size_t)9216 * 8 * sizeof(__bf16);
    if (ws_size >= wt_bytes) {
        __bf16* wT = (__bf16*)d_ws;
        prep_w<<<dim3(36), dim3(256), 0, stream>>>(Wq, Wk, Wv, wT);
        head_fused<true><<<dim3(BATCH), dim3(512), 0, stream>>>(x, Wq, Wk, Wv, wT, out);
    } else {
        head_fused<false><<<dim3(BATCH), dim3(512), 0, stream>>>(x, Wq, Wk, Wv, nullptr, out);
    }
}